// Round 23
// baseline (11645.815 us; speedup 1.0000x reference)
//
#include <hip/hip_runtime.h>
#include <hip/hip_bf16.h>

// Round 23: OUTPUT DTYPE FIX — d_out is FLOAT32 (reference outputs f32; the
// "(bf16)" in the checker label is a literal tag, not the out dtype). All 22
// prior rounds wrote bf16 into an f32 buffer => stride-2 node scramble =>
// universal decorrelation regardless of semantics. Pipeline: the exonerated
// naive listed-math version (pairing A, GCN scatter, torch r,z,n GRU).
//   h1 = relu(gcn(x,W1)+b1); q = LN(h1 + relu(gcn(h1,W2)+b2));
//   new_h = GRU(q, hp);  out = (new_h, new_h)  [f32]

__device__ __forceinline__ float sigf(float x) { return 1.0f / (1.0f + __expf(-x)); }

__global__ __launch_bounds__(256) void k_fill(float* o, long long n, float v) {
  long long i = (long long)blockIdx.x * 256 + threadIdx.x;
  if (i < n) o[i] = v;
}

// pairing A: contiguous halves (src | dst)
__device__ __forceinline__ int edge_s(const int* __restrict__ ei, int e, int E) { return ei[e]; }
__device__ __forceinline__ int edge_d(const int* __restrict__ ei, int e, int E) { return ei[(long long)E + e]; }

// ---------------- degree + dinv ----------------
__global__ __launch_bounds__(256) void k_hist(const int* __restrict__ ei,
                                              int* __restrict__ hist, int E, int N) {
  int e = blockIdx.x * 256 + threadIdx.x;
  if (e < E) {
    int d = edge_d(ei, e, E);
    if ((unsigned)d < (unsigned)N) atomicAdd(&hist[d], 1);
  }
}

__global__ __launch_bounds__(256) void k_dinv(const int* __restrict__ hist, float* __restrict__ dinv, int n) {
  int i = blockIdx.x * 256 + threadIdx.x;
  if (i < n) dinv[i] = rsqrtf((float)hist[i] + 1.0f);   // +1 self-loop
}

// ---------------- naive GEMM: C[i,j] = sum_k A[i,k]*W[k,j] ----------------
__global__ __launch_bounds__(256) void k_mm(const float* __restrict__ A, const float* __restrict__ W,
                                            float* __restrict__ C, int nrows) {
  long long e = (long long)blockIdx.x * 256 + threadIdx.x;
  int i = (int)(e >> 7), j = (int)(e & 127);
  if (i >= nrows) return;
  float acc = 0.f;
  for (int k = 0; k < 128; ++k)
    acc = fmaf(A[(long long)i * 128 + k], W[k * 128 + j], acc);
  C[e] = acc;
}

// ---------------- scatter aggregation ----------------
__global__ __launch_bounds__(256) void k_self(const float* __restrict__ xw, const float* __restrict__ dinv,
                                              float* __restrict__ out, long long NH) {
  long long e = (long long)blockIdx.x * 256 + threadIdx.x;
  if (e < NH) {
    int g = (int)(e >> 7);
    float d = dinv[g];
    out[e] = d * d * xw[e];
  }
}

__global__ __launch_bounds__(256) void k_scat(const int* __restrict__ ei,
                                              const float* __restrict__ xw, const float* __restrict__ dinv,
                                              float* __restrict__ out, int E, int N) {
  long long t = (long long)blockIdx.x * 256 + threadIdx.x;
  int e = (int)(t >> 5), c = (int)(t & 31) * 4;
  if (e >= E) return;
  int s = edge_s(ei, e, E);
  int d = edge_d(ei, e, E);
  if ((unsigned)s >= (unsigned)N || (unsigned)d >= (unsigned)N) return;
  float nrm = dinv[s] * dinv[d];
  const float* xs = xw + (long long)s * 128 + c;
  float* od = out + (long long)d * 128 + c;
  atomicAdd(od + 0, nrm * xs[0]);
  atomicAdd(od + 1, nrm * xs[1]);
  atomicAdd(od + 2, nrm * xs[2]);
  atomicAdd(od + 3, nrm * xs[3]);
}

__global__ __launch_bounds__(256) void k_post1(float* __restrict__ conv, const float* __restrict__ b,
                                               long long NH) {
  long long e = (long long)blockIdx.x * 256 + threadIdx.x;
  if (e < NH) conv[e] = fmaxf(conv[e] + b[(int)(e & 127)], 0.f);
}

__global__ __launch_bounds__(256) void k_post2(const float* __restrict__ conv, const float* __restrict__ b,
                                               const float* __restrict__ h1,
                                               const float* __restrict__ gam, const float* __restrict__ bet,
                                               float* __restrict__ hn, int N) {
  int g = blockIdx.x * 256 + threadIdx.x;
  if (g >= N) return;
  const float* c = conv + (long long)g * 128;
  const float* h = h1 + (long long)g * 128;
  float mu = 0.f;
  for (int j = 0; j < 128; ++j) mu += h[j] + fmaxf(c[j] + b[j], 0.f);
  mu *= (1.f / 128.f);
  float var = 0.f;
  for (int j = 0; j < 128; ++j) {
    float dd = h[j] + fmaxf(c[j] + b[j], 0.f) - mu;
    var += dd * dd;
  }
  float rs = rsqrtf(var * (1.f / 128.f) + 1e-5f);
  float* o = hn + (long long)g * 128;
  for (int j = 0; j < 128; ++j) {
    float v = h[j] + fmaxf(c[j] + b[j], 0.f);
    o[j] = (v - mu) * rs * gam[j] + bet[j];
  }
}

// ---------------- naive GRU (listed torch r,z,n) ----------------
__global__ __launch_bounds__(256) void k_gate_f(const float* __restrict__ q, const float* __restrict__ hp,
                                                const float* __restrict__ Wi, const float* __restrict__ Wh,
                                                const float* __restrict__ bi, const float* __restrict__ bh,
                                                float* __restrict__ G, int nrows) {
  long long e = (long long)blockIdx.x * 256 + threadIdx.x;
  int i = (int)(e >> 7), j = (int)(e & 127);
  if (i >= nrows) return;
  float a = bi[j] + bh[j];
  const float* wi = Wi + (long long)j * 128;
  const float* wh = Wh + (long long)j * 128;
  for (int k = 0; k < 128; ++k) a = fmaf(q[(long long)i * 128 + k], wi[k], a);
  for (int k = 0; k < 128; ++k) a = fmaf(hp[(long long)i * 128 + k], wh[k], a);
  G[e] = sigf(a);
}

// n = tanh(q@Wi_n^T + bi_n + R*(hp@Wh_n^T + bh_n)); out = (1-Z)*n + Z*hp  (f32, both halves)
__global__ __launch_bounds__(256) void k_nout(const float* __restrict__ q, const float* __restrict__ hp,
                                              const float* __restrict__ Wi, const float* __restrict__ Wh,
                                              const float* __restrict__ bi, const float* __restrict__ bh,
                                              const float* __restrict__ R, const float* __restrict__ Z,
                                              float* __restrict__ O, long long NH, int nrows) {
  long long e = (long long)blockIdx.x * 256 + threadIdx.x;
  int i = (int)(e >> 7), j = (int)(e & 127);
  if (i >= nrows) return;
  const float* wi = Wi + (long long)j * 128;
  const float* wh = Wh + (long long)j * 128;
  float ah = bh[j];
  for (int k = 0; k < 128; ++k) ah = fmaf(hp[(long long)i * 128 + k], wh[k], ah);
  float ai = bi[j];
  for (int k = 0; k < 128; ++k) ai = fmaf(q[(long long)i * 128 + k], wi[k], ai);
  float r = R[e];
  float z = Z[e];
  float n = tanhf(ai + r * ah);
  float o = (1.0f - z) * n + z * hp[e];
  O[e] = o;
  O[NH + e] = o;
}

// ---------------- launch ----------------

extern "C" void kernel_launch(void* const* d_in, const int* in_sizes, int n_in,
                              void* d_out, int out_size, void* d_ws, size_t ws_size,
                              hipStream_t stream) {
  float* ofp = (float*)d_out;
  const int fb = (out_size + 255) / 256;

  if (n_in != 13) { k_fill<<<fb, 256, 0, stream>>>(ofp, out_size, 100.0f); return; }

  const int N = in_sizes[0] / 128;
  const int S1 = in_sizes[1];
  const int E = S1 / 2;
  const long long NH = (long long)N * 128;

  bool okp = (in_sizes[0] % 128 == 0) && (S1 % 4 == 0) &&
             (in_sizes[2] == in_sizes[0]) &&
             in_sizes[3] == 16384 && in_sizes[4] == 128 &&
             in_sizes[5] == 16384 && in_sizes[6] == 128 &&
             in_sizes[7] == 128 && in_sizes[8] == 128 &&
             in_sizes[9] == 49152 && in_sizes[10] == 49152 &&
             in_sizes[11] == 384 && in_sizes[12] == 384;
  if (!okp) { k_fill<<<fb, 256, 0, stream>>>(ofp, out_size, 50.0f); return; }

  // ws: dinv | hist | pad | Xf | Yf | Zf
  char* wsb = (char*)d_ws;
  float* dinv = (float*)wsb;
  int* hist   = (int*)(dinv + N);
  size_t head = (size_t)((char*)(hist + N) - wsb);
  head = (head + 255) & ~(size_t)255;
  float* Xf = (float*)(wsb + head);
  float* Yf = Xf + NH;
  float* Zf = Yf + NH;
  size_t need = head + (size_t)3 * NH * 4;
  if (ws_size < need) { k_fill<<<fb, 256, 0, stream>>>(ofp, out_size, 25.0f); return; }

  const float* x   = (const float*)d_in[0];
  const int*   ei  = (const int*)d_in[1];
  const float* hp  = (const float*)d_in[2];
  const float* W1  = (const float*)d_in[3];
  const float* b1  = (const float*)d_in[4];
  const float* W2  = (const float*)d_in[5];
  const float* b2  = (const float*)d_in[6];
  const float* gam = (const float*)d_in[7];
  const float* bet = (const float*)d_in[8];
  const float* Wih = (const float*)d_in[9];
  const float* Whh = (const float*)d_in[10];
  const float* bih = (const float*)d_in[11];
  const float* bhh = (const float*)d_in[12];

  const int eb = (E + 255) / 256;
  const int nb = (N + 255) / 256;
  const int pb = (int)((NH + 255) / 256);
  const int sb = (int)(((long long)E * 32 + 255) / 256);

  hipMemsetAsync(hist, 0, (size_t)N * sizeof(int), stream);
  k_hist<<<eb, 256, 0, stream>>>(ei, hist, E, N);
  k_dinv<<<nb, 256, 0, stream>>>(hist, dinv, N);

  // conv1: Xf = x@W1 ; Yf = h1 = relu(self+scatter + b1)
  k_mm<<<pb, 256, 0, stream>>>(x, W1, Xf, N);
  k_self<<<pb, 256, 0, stream>>>(Xf, dinv, Yf, NH);
  k_scat<<<sb, 256, 0, stream>>>(ei, Xf, dinv, Yf, E, N);
  k_post1<<<pb, 256, 0, stream>>>(Yf, b1, NH);

  // conv2: Xf = h1@W2 ; Zf = self+scatter ; Yf = q = LN(h1 + relu(Zf + b2))
  k_mm<<<pb, 256, 0, stream>>>(Yf, W2, Xf, N);
  k_self<<<pb, 256, 0, stream>>>(Xf, dinv, Zf, NH);
  k_scat<<<sb, 256, 0, stream>>>(ei, Xf, dinv, Zf, E, N);
  k_post2<<<nb, 256, 0, stream>>>(Zf, b2, Yf, gam, bet, Yf, N);

  // GRU (torch r,z,n): r -> Zf ; z -> Xf ; fused n + f32 output (both halves)
  k_gate_f<<<pb, 256, 0, stream>>>(Yf, hp, Wih, Whh, bih, bhh, Zf, N);                       // r
  k_gate_f<<<pb, 256, 0, stream>>>(Yf, hp, Wih + 16384, Whh + 16384, bih + 128, bhh + 128,   // z
                                   Xf, N);
  k_nout<<<pb, 256, 0, stream>>>(Yf, hp, Wih + 32768, Whh + 32768, bih + 256, bhh + 256,
                                 Zf, Xf, ofp, NH, N);
}

// Round 24
// 1506.211 us; speedup vs baseline: 7.7319x; 7.7319x over previous
//
#include <hip/hip_runtime.h>
#include <hip/hip_bf16.h>

// Round 24: OPTIMIZED. Semantics locked by round-23 PASS (f32 out, pairing A,
// listed GCN + torch r,z,n GRU). Changes:
//   1. scatter -> CSR build + 32-lane gather (atomics 51M -> 3.2M int)
//   2. naive GEMMs -> 128x128 LDS-tiled fp32 GEMM, fused epilogues:
//      V=0 plain, V=1 sigmoid(A1@W1^T+A2@W2^T+b), V=2 full GRU n+output.
//   3. R/Z staged in d_out halves (V=2 reads own slots then overwrites).
// ws: CSR block + 2 NH-float buffers (~111MB < proven available).

__device__ __forceinline__ float sigf(float x) { return 1.0f / (1.0f + __expf(-x)); }

__global__ __launch_bounds__(256) void k_fill(float* o, long long n, float v) {
  long long i = (long long)blockIdx.x * 256 + threadIdx.x;
  if (i < n) o[i] = v;
}

// ---------------- CSR build (pairing A: src=ei[e], dst=ei[E+e]) ----------------

__global__ __launch_bounds__(256) void k_hist(const int* __restrict__ dstp, int* __restrict__ hist, int E) {
  int e = blockIdx.x * 256 + threadIdx.x;
  if (e < E) atomicAdd(&hist[dstp[e]], 1);
}

__global__ __launch_bounds__(256) void k_scan1(const int* __restrict__ hist, int* __restrict__ part,
                                               int* __restrict__ bsum, int n) {
  __shared__ int sh[256];
  int tid = threadIdx.x;
  int i = blockIdx.x * 256 + tid;
  int v = (i < n) ? hist[i] : 0;
  sh[tid] = v; __syncthreads();
  for (int off = 1; off < 256; off <<= 1) {
    int t = (tid >= off) ? sh[tid - off] : 0;
    __syncthreads();
    sh[tid] += t;
    __syncthreads();
  }
  if (i < n) part[i] = sh[tid] - v;
  if (tid == 255) bsum[blockIdx.x] = sh[255];
}

__global__ __launch_bounds__(512) void k_scan2(int* bs, int nb) {
  __shared__ int sh[512];
  int tid = threadIdx.x;
  int v = (tid < nb) ? bs[tid] : 0;
  sh[tid] = v; __syncthreads();
  for (int off = 1; off < 512; off <<= 1) {
    int t = (tid >= off) ? sh[tid - off] : 0;
    __syncthreads();
    sh[tid] += t;
    __syncthreads();
  }
  if (tid < nb) bs[tid] = sh[tid] - v;
}

__global__ __launch_bounds__(256) void k_scan3(const int* __restrict__ part, const int* __restrict__ bs,
                                               const int* __restrict__ hist, int* __restrict__ offs,
                                               int* __restrict__ cursor, float* __restrict__ dinv,
                                               int n, int E) {
  int i = blockIdx.x * 256 + threadIdx.x;
  if (i < n) {
    int o = part[i] + bs[i >> 8];
    offs[i] = o;
    cursor[i] = o;
    dinv[i] = rsqrtf((float)hist[i] + 1.0f);   // +1 self-loop
  } else if (i == n) {
    offs[n] = E;
  }
}

__global__ __launch_bounds__(256) void k_sort(const int* __restrict__ srcp, const int* __restrict__ dstp,
                                              int* cursor, int* __restrict__ ssrc, int E) {
  int e = blockIdx.x * 256 + threadIdx.x;
  if (e < E) {
    int d = dstp[e];
    int pos = atomicAdd(&cursor[d], 1);
    ssrc[pos] = srcp[e];
  }
}

// ---------------- tiled GEMM (128x128 tile, 256 thr, 8x8 micro) ----------------

__device__ __forceinline__ void load_A_T(const float* __restrict__ A, float (&At)[128][132],
                                         int r0, int nrows, int tid) {
  #pragma unroll 8
  for (int it = 0; it < 64; ++it) {
    int idx = tid + it * 256;
    int r = idx >> 7, k = idx & 127;
    int gr = r0 + r;
    At[k][r] = (gr < nrows) ? A[(long long)gr * 128 + k] : 0.f;
  }
}

__device__ __forceinline__ void load_W_nn(const float* __restrict__ W, float (&Ws)[128][132], int tid) {
  const float4* W4 = (const float4*)W;
  #pragma unroll
  for (int it = 0; it < 16; ++it) {
    int idx4 = tid + it * 256;
    int k = idx4 >> 5, cq = idx4 & 31;
    float4 v = W4[idx4];
    *(float4*)&Ws[k][cq * 4] = v;
  }
}

__device__ __forceinline__ void load_W_tt(const float* __restrict__ W, float (&Ws)[128][132], int tid) {
  #pragma unroll 8
  for (int it = 0; it < 64; ++it) {
    int idx = tid + it * 256;
    int c = idx >> 7, k = idx & 127;
    Ws[k][c] = W[(long long)c * 128 + k];
  }
}

__device__ __forceinline__ void kloop(const float (&At)[128][132], const float (&Ws)[128][132],
                                      float (&acc)[8][8], int rr, int cl, int ch) {
  #pragma unroll 4
  for (int k = 0; k < 128; ++k) {
    float4 a0 = *(const float4*)&At[k][rr];
    float4 a1 = *(const float4*)&At[k][rr + 4];
    float4 w0 = *(const float4*)&Ws[k][cl];
    float4 w1 = *(const float4*)&Ws[k][ch];
    float a[8] = {a0.x, a0.y, a0.z, a0.w, a1.x, a1.y, a1.z, a1.w};
    float w[8] = {w0.x, w0.y, w0.z, w0.w, w1.x, w1.y, w1.z, w1.w};
    #pragma unroll
    for (int i = 0; i < 8; ++i)
      #pragma unroll
      for (int j = 0; j < 8; ++j)
        acc[i][j] = fmaf(a[i], w[j], acc[i][j]);
  }
}

// V=0: Cout = A1@W1g                  (W [k][j])
// V=1: Cout = sigmoid(A1@W1g^T + A2@W2g^T + bend1 + bend2)     (W [j][k] rows)
// V=2: acc = A1@W1g^T (hp@Whh_n); acc = Rg*(acc+bmid); acc += A2@W2g^T (q@Wih_n);
//      out = (1-Zg)*tanh(acc+bend1) + Zg*HPg  -> f32 at O[.] and O[NH+.]
template<int V>
__global__ __launch_bounds__(256) void k_gemm(
    const float* __restrict__ A1, const float* __restrict__ W1g,
    const float* __restrict__ A2, const float* __restrict__ W2g,
    const float* __restrict__ bmid, const float* __restrict__ bend1, const float* __restrict__ bend2,
    const float* __restrict__ Rg, const float* __restrict__ Zg, const float* __restrict__ HPg,
    float* __restrict__ Cout, long long NH, int nrows)
{
  __shared__ float At[128][132];
  __shared__ float Ws[128][132];
  const int tid = threadIdx.x;
  const int r0 = blockIdx.x * 128;
  const int tr = tid >> 4, tc = tid & 15;
  const int rr = tr * 8;
  const int cl = tc * 4, ch = 64 + tc * 4;

  float acc[8][8];
  #pragma unroll
  for (int i = 0; i < 8; ++i)
    #pragma unroll
    for (int j = 0; j < 8; ++j) acc[i][j] = 0.f;

  load_A_T(A1, At, r0, nrows, tid);
  if (V == 0) load_W_nn(W1g, Ws, tid);
  else        load_W_tt(W1g, Ws, tid);
  __syncthreads();
  kloop(At, Ws, acc, rr, cl, ch);

  if (V >= 1) {
    if (V == 2) {
      float4 bm0 = *(const float4*)&bmid[cl];
      float4 bm1 = *(const float4*)&bmid[ch];
      float bm[8] = {bm0.x, bm0.y, bm0.z, bm0.w, bm1.x, bm1.y, bm1.z, bm1.w};
      #pragma unroll
      for (int i = 0; i < 8; ++i) {
        int gr = r0 + rr + i;
        if (gr < nrows) {
          float4 rl = *(const float4*)&Rg[(long long)gr * 128 + cl];
          float4 rh = *(const float4*)&Rg[(long long)gr * 128 + ch];
          float rv[8] = {rl.x, rl.y, rl.z, rl.w, rh.x, rh.y, rh.z, rh.w};
          #pragma unroll
          for (int j = 0; j < 8; ++j) acc[i][j] = rv[j] * (acc[i][j] + bm[j]);
        }
      }
    }
    __syncthreads();
    load_A_T(A2, At, r0, nrows, tid);
    load_W_tt(W2g, Ws, tid);
    __syncthreads();
    kloop(At, Ws, acc, rr, cl, ch);
  }

  if (V == 0) {
    #pragma unroll
    for (int i = 0; i < 8; ++i) {
      int gr = r0 + rr + i;
      if (gr < nrows) {
        *(float4*)&Cout[(long long)gr * 128 + cl] = make_float4(acc[i][0], acc[i][1], acc[i][2], acc[i][3]);
        *(float4*)&Cout[(long long)gr * 128 + ch] = make_float4(acc[i][4], acc[i][5], acc[i][6], acc[i][7]);
      }
    }
  } else if (V == 1) {
    float4 x0 = *(const float4*)&bend1[cl], x1 = *(const float4*)&bend1[ch];
    float4 y0 = *(const float4*)&bend2[cl], y1 = *(const float4*)&bend2[ch];
    float b[8] = {x0.x + y0.x, x0.y + y0.y, x0.z + y0.z, x0.w + y0.w,
                  x1.x + y1.x, x1.y + y1.y, x1.z + y1.z, x1.w + y1.w};
    #pragma unroll
    for (int i = 0; i < 8; ++i) {
      int gr = r0 + rr + i;
      if (gr < nrows) {
        *(float4*)&Cout[(long long)gr * 128 + cl] =
            make_float4(sigf(acc[i][0] + b[0]), sigf(acc[i][1] + b[1]),
                        sigf(acc[i][2] + b[2]), sigf(acc[i][3] + b[3]));
        *(float4*)&Cout[(long long)gr * 128 + ch] =
            make_float4(sigf(acc[i][4] + b[4]), sigf(acc[i][5] + b[5]),
                        sigf(acc[i][6] + b[6]), sigf(acc[i][7] + b[7]));
      }
    }
  } else {
    float4 x0 = *(const float4*)&bend1[cl], x1 = *(const float4*)&bend1[ch];
    float b[8] = {x0.x, x0.y, x0.z, x0.w, x1.x, x1.y, x1.z, x1.w};
    #pragma unroll
    for (int i = 0; i < 8; ++i) {
      int gr = r0 + rr + i;
      if (gr < nrows) {
        long long base = (long long)gr * 128;
        float4 zl = *(const float4*)&Zg[base + cl];
        float4 zh = *(const float4*)&Zg[base + ch];
        float4 hl = *(const float4*)&HPg[base + cl];
        float4 hh = *(const float4*)&HPg[base + ch];
        float zv[8] = {zl.x, zl.y, zl.z, zl.w, zh.x, zh.y, zh.z, zh.w};
        float hv[8] = {hl.x, hl.y, hl.z, hl.w, hh.x, hh.y, hh.z, hh.w};
        float o[8];
        #pragma unroll
        for (int j = 0; j < 8; ++j) {
          float n = tanhf(acc[i][j] + b[j]);
          o[j] = (1.0f - zv[j]) * n + zv[j] * hv[j];
        }
        // each thread reads its own R/Z slots above, then overwrites below
        *(float4*)&Cout[base + cl] = make_float4(o[0], o[1], o[2], o[3]);
        *(float4*)&Cout[base + ch] = make_float4(o[4], o[5], o[6], o[7]);
        *(float4*)&Cout[NH + base + cl] = make_float4(o[0], o[1], o[2], o[3]);
        *(float4*)&Cout[NH + base + ch] = make_float4(o[4], o[5], o[6], o[7]);
      }
    }
  }
}

// ---------------- CSR gather (32-lane group per node, float4/lane) ----------------
// out[g] = relu(dinv[g]*(dinv[g]*xw[g] + sum_s dinv[s]*xw[s]) + bias)
// FUSE_LN: t = H1[g] + relu(...); LayerNorm; Out may alias H1 (row-local).

template<bool FUSE_LN>
__global__ __launch_bounds__(256) void k_gather(
    const float* __restrict__ XW, const float* __restrict__ dinv,
    const int* __restrict__ offs, const int* __restrict__ ssrc,
    const float* __restrict__ bias,
    const float* __restrict__ H1,
    const float* __restrict__ gamma, const float* __restrict__ beta,
    float* __restrict__ Out, int nnodes)
{
  int g = (int)(((long long)blockIdx.x * blockDim.x + threadIdx.x) >> 5);
  int l = threadIdx.x & 31;
  if (g >= nnodes) return;
  float di = dinv[g];
  float4 acc = ((const float4*)(XW + (long long)g * 128))[l];
  acc.x *= di; acc.y *= di; acc.z *= di; acc.w *= di;   // self term (x di again later -> di^2)

  int j = offs[g], e1 = offs[g + 1];
  for (; j + 1 < e1; j += 2) {
    int s0 = ssrc[j], s1 = ssrc[j + 1];
    float d0 = dinv[s0], d1 = dinv[s1];
    float4 v0 = ((const float4*)(XW + (long long)s0 * 128))[l];
    float4 v1 = ((const float4*)(XW + (long long)s1 * 128))[l];
    acc.x = fmaf(d0, v0.x, acc.x); acc.y = fmaf(d0, v0.y, acc.y);
    acc.z = fmaf(d0, v0.z, acc.z); acc.w = fmaf(d0, v0.w, acc.w);
    acc.x = fmaf(d1, v1.x, acc.x); acc.y = fmaf(d1, v1.y, acc.y);
    acc.z = fmaf(d1, v1.z, acc.z); acc.w = fmaf(d1, v1.w, acc.w);
  }
  if (j < e1) {
    int s = ssrc[j];
    float ds = dinv[s];
    float4 v = ((const float4*)(XW + (long long)s * 128))[l];
    acc.x = fmaf(ds, v.x, acc.x); acc.y = fmaf(ds, v.y, acc.y);
    acc.z = fmaf(ds, v.z, acc.z); acc.w = fmaf(ds, v.w, acc.w);
  }

  int c = l * 4;
  float4 b4 = *(const float4*)&bias[c];
  float4 t;
  t.x = fmaxf(fmaf(acc.x, di, b4.x), 0.f);
  t.y = fmaxf(fmaf(acc.y, di, b4.y), 0.f);
  t.z = fmaxf(fmaf(acc.z, di, b4.z), 0.f);
  t.w = fmaxf(fmaf(acc.w, di, b4.w), 0.f);

  if (!FUSE_LN) {
    ((float4*)(Out + (long long)g * 128))[l] = t;
  } else {
    float4 h4 = ((const float4*)(H1 + (long long)g * 128))[l];
    t.x += h4.x; t.y += h4.y; t.z += h4.z; t.w += h4.w;
    float s = t.x + t.y + t.z + t.w;
    #pragma unroll
    for (int off = 16; off > 0; off >>= 1) s += __shfl_xor(s, off, 32);
    float mu = s * (1.0f / 128.0f);
    float dx = t.x - mu, dy = t.y - mu, dz = t.z - mu, dw = t.w - mu;
    float q = dx * dx + dy * dy + dz * dz + dw * dw;
    #pragma unroll
    for (int off = 16; off > 0; off >>= 1) q += __shfl_xor(q, off, 32);
    float rstd = rsqrtf(q * (1.0f / 128.0f) + 1e-5f);
    float4 g4 = *(const float4*)&gamma[c];
    float4 be4 = *(const float4*)&beta[c];
    float4 o;
    o.x = dx * rstd * g4.x + be4.x;
    o.y = dy * rstd * g4.y + be4.y;
    o.z = dz * rstd * g4.z + be4.z;
    o.w = dw * rstd * g4.w + be4.w;
    ((float4*)(Out + (long long)g * 128))[l] = o;
  }
}

// ---------------- launch ----------------

extern "C" void kernel_launch(void* const* d_in, const int* in_sizes, int n_in,
                              void* d_out, int out_size, void* d_ws, size_t ws_size,
                              hipStream_t stream) {
  float* ofp = (float*)d_out;
  const int fb = (out_size + 255) / 256;

  if (n_in != 13) { k_fill<<<fb, 256, 0, stream>>>(ofp, out_size, 100.0f); return; }

  const int N = in_sizes[0] / 128;
  const int S1 = in_sizes[1];
  const int E = S1 / 2;
  const long long NH = (long long)N * 128;

  bool okp = (in_sizes[0] % 128 == 0) && (S1 % 4 == 0) &&
             (in_sizes[2] == in_sizes[0]) &&
             in_sizes[3] == 16384 && in_sizes[4] == 128 &&
             in_sizes[5] == 16384 && in_sizes[6] == 128 &&
             in_sizes[7] == 128 && in_sizes[8] == 128 &&
             in_sizes[9] == 49152 && in_sizes[10] == 49152 &&
             in_sizes[11] == 384 && in_sizes[12] == 384;
  if (!okp) { k_fill<<<fb, 256, 0, stream>>>(ofp, out_size, 50.0f); return; }

  // ws: dinv | hist | part | offs | cursor | bsum | ssrc | pad | Xf | Yf
  char* wsb = (char*)d_ws;
  float* dinv = (float*)wsb;
  int* hist   = (int*)(dinv + N);
  int* part   = hist + N;
  int* offs   = part + N;
  int* cursor = offs + N + 1;
  int* bsum   = cursor + N;
  int* ssrc   = bsum + 1024;
  size_t head = (size_t)((char*)(ssrc + E) - wsb);
  head = (head + 255) & ~(size_t)255;
  float* Xf = (float*)(wsb + head);
  float* Yf = Xf + NH;
  size_t need = head + (size_t)2 * NH * 4;
  if (ws_size < need) { k_fill<<<fb, 256, 0, stream>>>(ofp, out_size, 25.0f); return; }

  const float* x   = (const float*)d_in[0];
  const int*   ei  = (const int*)d_in[1];
  const float* hp  = (const float*)d_in[2];
  const float* W1  = (const float*)d_in[3];
  const float* b1  = (const float*)d_in[4];
  const float* W2  = (const float*)d_in[5];
  const float* b2  = (const float*)d_in[6];
  const float* gam = (const float*)d_in[7];
  const float* bet = (const float*)d_in[8];
  const float* Wih = (const float*)d_in[9];
  const float* Whh = (const float*)d_in[10];
  const float* bih = (const float*)d_in[11];
  const float* bhh = (const float*)d_in[12];
  const int* srcp = ei;
  const int* dstp = ei + E;

  float* Rbuf = ofp;        // d_out first half as R scratch
  float* Zbuf = ofp + NH;   // d_out second half as Z scratch

  const int eb  = (E + 255) / 256;
  const int nb  = (N + 255) / 256;
  const int gb  = (N + 127) / 128;
  const int agb = (int)(((long long)N * 32 + 255) / 256);

  // CSR build + dinv
  hipMemsetAsync(hist, 0, (size_t)N * sizeof(int), stream);
  k_hist<<<eb, 256, 0, stream>>>(dstp, hist, E);
  k_scan1<<<nb, 256, 0, stream>>>(hist, part, bsum, N);
  k_scan2<<<1, 512, 0, stream>>>(bsum, nb);
  k_scan3<<<nb + 1, 256, 0, stream>>>(part, bsum, hist, offs, cursor, dinv, N, E);
  k_sort<<<eb, 256, 0, stream>>>(srcp, dstp, cursor, ssrc, E);

  // conv1: Xf = x@W1 ; Yf = h1 = relu(gather + b1)
  k_gemm<0><<<gb, 256, 0, stream>>>(x, W1, nullptr, nullptr, nullptr, nullptr, nullptr,
                                    nullptr, nullptr, nullptr, Xf, NH, N);
  k_gather<false><<<agb, 256, 0, stream>>>(Xf, dinv, offs, ssrc, b1,
                                           nullptr, nullptr, nullptr, Yf, N);
  // conv2: Xf = h1@W2 ; Yf = q = LN(h1 + relu(gather + b2))  (in-place)
  k_gemm<0><<<gb, 256, 0, stream>>>(Yf, W2, nullptr, nullptr, nullptr, nullptr, nullptr,
                                    nullptr, nullptr, nullptr, Xf, NH, N);
  k_gather<true><<<agb, 256, 0, stream>>>(Xf, dinv, offs, ssrc, b2,
                                          Yf, gam, bet, Yf, N);

  // GRU: R -> d_out[0,NH), Z -> d_out[NH,2NH), then fused n+output overwrites both
  k_gemm<1><<<gb, 256, 0, stream>>>(Yf, Wih, hp, Whh, nullptr, bih, bhh,
                                    nullptr, nullptr, nullptr, Rbuf, NH, N);
  k_gemm<1><<<gb, 256, 0, stream>>>(Yf, Wih + 16384, hp, Whh + 16384, nullptr,
                                    bih + 128, bhh + 128,
                                    nullptr, nullptr, nullptr, Zbuf, NH, N);
  k_gemm<2><<<gb, 256, 0, stream>>>(hp, Whh + 32768, Yf, Wih + 32768,
                                    bhh + 256, bih + 256, nullptr,
                                    Rbuf, Zbuf, hp, ofp, NH, N);
}

// Round 25
// 1127.792 us; speedup vs baseline: 10.3262x; 1.3355x over previous
//
#include <hip/hip_runtime.h>
#include <hip/hip_bf16.h>

// Round 25: K-CHUNKED tiled GEMM (KC=32) — LDS 135KB -> 33.8KB per block,
// occupancy 1 -> 3 blocks/CU (9.5% -> ~37%). Same math, same FMA order.
// Everything else unchanged from round-24 PASS (CSR gather, fused epilogues,
// R/Z staged in d_out halves).

__device__ __forceinline__ float sigf(float x) { return 1.0f / (1.0f + __expf(-x)); }

__global__ __launch_bounds__(256) void k_fill(float* o, long long n, float v) {
  long long i = (long long)blockIdx.x * 256 + threadIdx.x;
  if (i < n) o[i] = v;
}

// ---------------- CSR build (pairing A: src=ei[e], dst=ei[E+e]) ----------------

__global__ __launch_bounds__(256) void k_hist(const int* __restrict__ dstp, int* __restrict__ hist, int E) {
  int e = blockIdx.x * 256 + threadIdx.x;
  if (e < E) atomicAdd(&hist[dstp[e]], 1);
}

__global__ __launch_bounds__(256) void k_scan1(const int* __restrict__ hist, int* __restrict__ part,
                                               int* __restrict__ bsum, int n) {
  __shared__ int sh[256];
  int tid = threadIdx.x;
  int i = blockIdx.x * 256 + tid;
  int v = (i < n) ? hist[i] : 0;
  sh[tid] = v; __syncthreads();
  for (int off = 1; off < 256; off <<= 1) {
    int t = (tid >= off) ? sh[tid - off] : 0;
    __syncthreads();
    sh[tid] += t;
    __syncthreads();
  }
  if (i < n) part[i] = sh[tid] - v;
  if (tid == 255) bsum[blockIdx.x] = sh[255];
}

__global__ __launch_bounds__(512) void k_scan2(int* bs, int nb) {
  __shared__ int sh[512];
  int tid = threadIdx.x;
  int v = (tid < nb) ? bs[tid] : 0;
  sh[tid] = v; __syncthreads();
  for (int off = 1; off < 512; off <<= 1) {
    int t = (tid >= off) ? sh[tid - off] : 0;
    __syncthreads();
    sh[tid] += t;
    __syncthreads();
  }
  if (tid < nb) bs[tid] = sh[tid] - v;
}

__global__ __launch_bounds__(256) void k_scan3(const int* __restrict__ part, const int* __restrict__ bs,
                                               const int* __restrict__ hist, int* __restrict__ offs,
                                               int* __restrict__ cursor, float* __restrict__ dinv,
                                               int n, int E) {
  int i = blockIdx.x * 256 + threadIdx.x;
  if (i < n) {
    int o = part[i] + bs[i >> 8];
    offs[i] = o;
    cursor[i] = o;
    dinv[i] = rsqrtf((float)hist[i] + 1.0f);   // +1 self-loop
  } else if (i == n) {
    offs[n] = E;
  }
}

__global__ __launch_bounds__(256) void k_sort(const int* __restrict__ srcp, const int* __restrict__ dstp,
                                              int* cursor, int* __restrict__ ssrc, int E) {
  int e = blockIdx.x * 256 + threadIdx.x;
  if (e < E) {
    int d = dstp[e];
    int pos = atomicAdd(&cursor[d], 1);
    ssrc[pos] = srcp[e];
  }
}

// ---------------- K-chunked tiled GEMM (128x128 tile, KC=32, 8x8 micro) ----------------

#define KC 32

__device__ __forceinline__ void kloop32(const float (&At)[KC][132], const float (&Ws)[KC][132],
                                        float (&acc)[8][8], int rr, int cl, int ch) {
  #pragma unroll 4
  for (int k = 0; k < KC; ++k) {
    float4 a0 = *(const float4*)&At[k][rr];
    float4 a1 = *(const float4*)&At[k][rr + 4];
    float4 w0 = *(const float4*)&Ws[k][cl];
    float4 w1 = *(const float4*)&Ws[k][ch];
    float a[8] = {a0.x, a0.y, a0.z, a0.w, a1.x, a1.y, a1.z, a1.w};
    float w[8] = {w0.x, w0.y, w0.z, w0.w, w1.x, w1.y, w1.z, w1.w};
    #pragma unroll
    for (int i = 0; i < 8; ++i)
      #pragma unroll
      for (int j = 0; j < 8; ++j)
        acc[i][j] = fmaf(a[i], w[j], acc[i][j]);
  }
}

// stage A chunk: At[kl][r] = A[(r0+r)*128 + kk+kl]
__device__ __forceinline__ void stage_A(const float* __restrict__ A, float (&At)[KC][132],
                                        int r0, int kk, int nrows, int tid) {
  #pragma unroll
  for (int it = 0; it < 16; ++it) {
    int idx = tid + it * 256;
    int r = idx >> 5, kl = idx & 31;
    int gr = r0 + r;
    At[kl][r] = (gr < nrows) ? A[(long long)gr * 128 + kk + kl] : 0.f;
  }
}

// W row-major [k][j]: Ws[kl][j] = W[(kk+kl)*128 + j]  (coalesced + conflict-free)
__device__ __forceinline__ void stage_W_nn(const float* __restrict__ W, float (&Ws)[KC][132],
                                           int kk, int tid) {
  #pragma unroll
  for (int it = 0; it < 16; ++it) {
    int idx = tid + it * 256;
    int j = idx & 127, kl = idx >> 7;
    Ws[kl][j] = W[(kk + kl) * 128 + j];
  }
}

// W row-major [j][k]: Ws[kl][j] = W[j*128 + kk+kl]
__device__ __forceinline__ void stage_W_tt(const float* __restrict__ W, float (&Ws)[KC][132],
                                           int kk, int tid) {
  #pragma unroll
  for (int it = 0; it < 16; ++it) {
    int idx = tid + it * 256;
    int kl = idx & 31, j = idx >> 5;
    Ws[kl][j] = W[(long long)j * 128 + kk + kl];
  }
}

// V=0: Cout = A1@W1g                  (W [k][j])
// V=1: Cout = sigmoid(A1@W1g^T + A2@W2g^T + bend1 + bend2)     (W [j][k] rows)
// V=2: acc = A1@W1g^T (hp@Whh_n); acc = Rg*(acc+bmid); acc += A2@W2g^T (q@Wih_n);
//      out = (1-Zg)*tanh(acc+bend1) + Zg*HPg  -> f32 at O[.] and O[NH+.]
template<int V>
__global__ __launch_bounds__(256) void k_gemm(
    const float* __restrict__ A1, const float* __restrict__ W1g,
    const float* __restrict__ A2, const float* __restrict__ W2g,
    const float* __restrict__ bmid, const float* __restrict__ bend1, const float* __restrict__ bend2,
    const float* __restrict__ Rg, const float* __restrict__ Zg, const float* __restrict__ HPg,
    float* __restrict__ Cout, long long NH, int nrows)
{
  __shared__ float At[KC][132];
  __shared__ float Ws[KC][132];
  const int tid = threadIdx.x;
  const int r0 = blockIdx.x * 128;
  const int tr = tid >> 4, tc = tid & 15;
  const int rr = tr * 8;
  const int cl = tc * 4, ch = 64 + tc * 4;

  float acc[8][8];
  #pragma unroll
  for (int i = 0; i < 8; ++i)
    #pragma unroll
    for (int j = 0; j < 8; ++j) acc[i][j] = 0.f;

  // first operand
  for (int kk = 0; kk < 128; kk += KC) {
    stage_A(A1, At, r0, kk, nrows, tid);
    if (V == 0) stage_W_nn(W1g, Ws, kk, tid);
    else        stage_W_tt(W1g, Ws, kk, tid);
    __syncthreads();
    kloop32(At, Ws, acc, rr, cl, ch);
    __syncthreads();
  }

  if (V >= 1) {
    if (V == 2) {
      float4 bm0 = *(const float4*)&bmid[cl];
      float4 bm1 = *(const float4*)&bmid[ch];
      float bm[8] = {bm0.x, bm0.y, bm0.z, bm0.w, bm1.x, bm1.y, bm1.z, bm1.w};
      #pragma unroll
      for (int i = 0; i < 8; ++i) {
        int gr = r0 + rr + i;
        if (gr < nrows) {
          float4 rl = *(const float4*)&Rg[(long long)gr * 128 + cl];
          float4 rh = *(const float4*)&Rg[(long long)gr * 128 + ch];
          float rv[8] = {rl.x, rl.y, rl.z, rl.w, rh.x, rh.y, rh.z, rh.w};
          #pragma unroll
          for (int j = 0; j < 8; ++j) acc[i][j] = rv[j] * (acc[i][j] + bm[j]);
        }
      }
    }
    // second operand
    for (int kk = 0; kk < 128; kk += KC) {
      stage_A(A2, At, r0, kk, nrows, tid);
      stage_W_tt(W2g, Ws, kk, tid);
      __syncthreads();
      kloop32(At, Ws, acc, rr, cl, ch);
      __syncthreads();
    }
  }

  if (V == 0) {
    #pragma unroll
    for (int i = 0; i < 8; ++i) {
      int gr = r0 + rr + i;
      if (gr < nrows) {
        *(float4*)&Cout[(long long)gr * 128 + cl] = make_float4(acc[i][0], acc[i][1], acc[i][2], acc[i][3]);
        *(float4*)&Cout[(long long)gr * 128 + ch] = make_float4(acc[i][4], acc[i][5], acc[i][6], acc[i][7]);
      }
    }
  } else if (V == 1) {
    float4 x0 = *(const float4*)&bend1[cl], x1 = *(const float4*)&bend1[ch];
    float4 y0 = *(const float4*)&bend2[cl], y1 = *(const float4*)&bend2[ch];
    float b[8] = {x0.x + y0.x, x0.y + y0.y, x0.z + y0.z, x0.w + y0.w,
                  x1.x + y1.x, x1.y + y1.y, x1.z + y1.z, x1.w + y1.w};
    #pragma unroll
    for (int i = 0; i < 8; ++i) {
      int gr = r0 + rr + i;
      if (gr < nrows) {
        *(float4*)&Cout[(long long)gr * 128 + cl] =
            make_float4(sigf(acc[i][0] + b[0]), sigf(acc[i][1] + b[1]),
                        sigf(acc[i][2] + b[2]), sigf(acc[i][3] + b[3]));
        *(float4*)&Cout[(long long)gr * 128 + ch] =
            make_float4(sigf(acc[i][4] + b[4]), sigf(acc[i][5] + b[5]),
                        sigf(acc[i][6] + b[6]), sigf(acc[i][7] + b[7]));
      }
    }
  } else {
    float4 x0 = *(const float4*)&bend1[cl], x1 = *(const float4*)&bend1[ch];
    float b[8] = {x0.x, x0.y, x0.z, x0.w, x1.x, x1.y, x1.z, x1.w};
    #pragma unroll
    for (int i = 0; i < 8; ++i) {
      int gr = r0 + rr + i;
      if (gr < nrows) {
        long long base = (long long)gr * 128;
        float4 zl = *(const float4*)&Zg[base + cl];
        float4 zh = *(const float4*)&Zg[base + ch];
        float4 hl = *(const float4*)&HPg[base + cl];
        float4 hh = *(const float4*)&HPg[base + ch];
        float zv[8] = {zl.x, zl.y, zl.z, zl.w, zh.x, zh.y, zh.z, zh.w};
        float hv[8] = {hl.x, hl.y, hl.z, hl.w, hh.x, hh.y, hh.z, hh.w};
        float o[8];
        #pragma unroll
        for (int j = 0; j < 8; ++j) {
          float n = tanhf(acc[i][j] + b[j]);
          o[j] = (1.0f - zv[j]) * n + zv[j] * hv[j];
        }
        // each thread reads its own R/Z slots above, then overwrites below
        *(float4*)&Cout[base + cl] = make_float4(o[0], o[1], o[2], o[3]);
        *(float4*)&Cout[base + ch] = make_float4(o[4], o[5], o[6], o[7]);
        *(float4*)&Cout[NH + base + cl] = make_float4(o[0], o[1], o[2], o[3]);
        *(float4*)&Cout[NH + base + ch] = make_float4(o[4], o[5], o[6], o[7]);
      }
    }
  }
}

// ---------------- CSR gather (32-lane group per node, float4/lane) ----------------
// out[g] = relu(dinv[g]*(dinv[g]*xw[g] + sum_s dinv[s]*xw[s]) + bias)
// FUSE_LN: t = H1[g] + relu(...); LayerNorm; Out may alias H1 (row-local).

template<bool FUSE_LN>
__global__ __launch_bounds__(256) void k_gather(
    const float* __restrict__ XW, const float* __restrict__ dinv,
    const int* __restrict__ offs, const int* __restrict__ ssrc,
    const float* __restrict__ bias,
    const float* __restrict__ H1,
    const float* __restrict__ gamma, const float* __restrict__ beta,
    float* __restrict__ Out, int nnodes)
{
  int g = (int)(((long long)blockIdx.x * blockDim.x + threadIdx.x) >> 5);
  int l = threadIdx.x & 31;
  if (g >= nnodes) return;
  float di = dinv[g];
  float4 acc = ((const float4*)(XW + (long long)g * 128))[l];
  acc.x *= di; acc.y *= di; acc.z *= di; acc.w *= di;   // self term (x di again later -> di^2)

  int j = offs[g], e1 = offs[g + 1];
  for (; j + 1 < e1; j += 2) {
    int s0 = ssrc[j], s1 = ssrc[j + 1];
    float d0 = dinv[s0], d1 = dinv[s1];
    float4 v0 = ((const float4*)(XW + (long long)s0 * 128))[l];
    float4 v1 = ((const float4*)(XW + (long long)s1 * 128))[l];
    acc.x = fmaf(d0, v0.x, acc.x); acc.y = fmaf(d0, v0.y, acc.y);
    acc.z = fmaf(d0, v0.z, acc.z); acc.w = fmaf(d0, v0.w, acc.w);
    acc.x = fmaf(d1, v1.x, acc.x); acc.y = fmaf(d1, v1.y, acc.y);
    acc.z = fmaf(d1, v1.z, acc.z); acc.w = fmaf(d1, v1.w, acc.w);
  }
  if (j < e1) {
    int s = ssrc[j];
    float ds = dinv[s];
    float4 v = ((const float4*)(XW + (long long)s * 128))[l];
    acc.x = fmaf(ds, v.x, acc.x); acc.y = fmaf(ds, v.y, acc.y);
    acc.z = fmaf(ds, v.z, acc.z); acc.w = fmaf(ds, v.w, acc.w);
  }

  int c = l * 4;
  float4 b4 = *(const float4*)&bias[c];
  float4 t;
  t.x = fmaxf(fmaf(acc.x, di, b4.x), 0.f);
  t.y = fmaxf(fmaf(acc.y, di, b4.y), 0.f);
  t.z = fmaxf(fmaf(acc.z, di, b4.z), 0.f);
  t.w = fmaxf(fmaf(acc.w, di, b4.w), 0.f);

  if (!FUSE_LN) {
    ((float4*)(Out + (long long)g * 128))[l] = t;
  } else {
    float4 h4 = ((const float4*)(H1 + (long long)g * 128))[l];
    t.x += h4.x; t.y += h4.y; t.z += h4.z; t.w += h4.w;
    float s = t.x + t.y + t.z + t.w;
    #pragma unroll
    for (int off = 16; off > 0; off >>= 1) s += __shfl_xor(s, off, 32);
    float mu = s * (1.0f / 128.0f);
    float dx = t.x - mu, dy = t.y - mu, dz = t.z - mu, dw = t.w - mu;
    float q = dx * dx + dy * dy + dz * dz + dw * dw;
    #pragma unroll
    for (int off = 16; off > 0; off >>= 1) q += __shfl_xor(q, off, 32);
    float rstd = rsqrtf(q * (1.0f / 128.0f) + 1e-5f);
    float4 g4 = *(const float4*)&gamma[c];
    float4 be4 = *(const float4*)&beta[c];
    float4 o;
    o.x = dx * rstd * g4.x + be4.x;
    o.y = dy * rstd * g4.y + be4.y;
    o.z = dz * rstd * g4.z + be4.z;
    o.w = dw * rstd * g4.w + be4.w;
    ((float4*)(Out + (long long)g * 128))[l] = o;
  }
}

// ---------------- launch ----------------

extern "C" void kernel_launch(void* const* d_in, const int* in_sizes, int n_in,
                              void* d_out, int out_size, void* d_ws, size_t ws_size,
                              hipStream_t stream) {
  float* ofp = (float*)d_out;
  const int fb = (out_size + 255) / 256;

  if (n_in != 13) { k_fill<<<fb, 256, 0, stream>>>(ofp, out_size, 100.0f); return; }

  const int N = in_sizes[0] / 128;
  const int S1 = in_sizes[1];
  const int E = S1 / 2;
  const long long NH = (long long)N * 128;

  bool okp = (in_sizes[0] % 128 == 0) && (S1 % 4 == 0) &&
             (in_sizes[2] == in_sizes[0]) &&
             in_sizes[3] == 16384 && in_sizes[4] == 128 &&
             in_sizes[5] == 16384 && in_sizes[6] == 128 &&
             in_sizes[7] == 128 && in_sizes[8] == 128 &&
             in_sizes[9] == 49152 && in_sizes[10] == 49152 &&
             in_sizes[11] == 384 && in_sizes[12] == 384;
  if (!okp) { k_fill<<<fb, 256, 0, stream>>>(ofp, out_size, 50.0f); return; }

  // ws: dinv | hist | part | offs | cursor | bsum | ssrc | pad | Xf | Yf
  char* wsb = (char*)d_ws;
  float* dinv = (float*)wsb;
  int* hist   = (int*)(dinv + N);
  int* part   = hist + N;
  int* offs   = part + N;
  int* cursor = offs + N + 1;
  int* bsum   = cursor + N;
  int* ssrc   = bsum + 1024;
  size_t head = (size_t)((char*)(ssrc + E) - wsb);
  head = (head + 255) & ~(size_t)255;
  float* Xf = (float*)(wsb + head);
  float* Yf = Xf + NH;
  size_t need = head + (size_t)2 * NH * 4;
  if (ws_size < need) { k_fill<<<fb, 256, 0, stream>>>(ofp, out_size, 25.0f); return; }

  const float* x   = (const float*)d_in[0];
  const int*   ei  = (const int*)d_in[1];
  const float* hp  = (const float*)d_in[2];
  const float* W1  = (const float*)d_in[3];
  const float* b1  = (const float*)d_in[4];
  const float* W2  = (const float*)d_in[5];
  const float* b2  = (const float*)d_in[6];
  const float* gam = (const float*)d_in[7];
  const float* bet = (const float*)d_in[8];
  const float* Wih = (const float*)d_in[9];
  const float* Whh = (const float*)d_in[10];
  const float* bih = (const float*)d_in[11];
  const float* bhh = (const float*)d_in[12];
  const int* srcp = ei;
  const int* dstp = ei + E;

  float* Rbuf = ofp;        // d_out first half as R scratch
  float* Zbuf = ofp + NH;   // d_out second half as Z scratch

  const int eb  = (E + 255) / 256;
  const int nb  = (N + 255) / 256;
  const int gb  = (N + 127) / 128;
  const int agb = (int)(((long long)N * 32 + 255) / 256);

  // CSR build + dinv
  hipMemsetAsync(hist, 0, (size_t)N * sizeof(int), stream);
  k_hist<<<eb, 256, 0, stream>>>(dstp, hist, E);
  k_scan1<<<nb, 256, 0, stream>>>(hist, part, bsum, N);
  k_scan2<<<1, 512, 0, stream>>>(bsum, nb);
  k_scan3<<<nb + 1, 256, 0, stream>>>(part, bsum, hist, offs, cursor, dinv, N, E);
  k_sort<<<eb, 256, 0, stream>>>(srcp, dstp, cursor, ssrc, E);

  // conv1: Xf = x@W1 ; Yf = h1 = relu(gather + b1)
  k_gemm<0><<<gb, 256, 0, stream>>>(x, W1, nullptr, nullptr, nullptr, nullptr, nullptr,
                                    nullptr, nullptr, nullptr, Xf, NH, N);
  k_gather<false><<<agb, 256, 0, stream>>>(Xf, dinv, offs, ssrc, b1,
                                           nullptr, nullptr, nullptr, Yf, N);
  // conv2: Xf = h1@W2 ; Yf = q = LN(h1 + relu(gather + b2))  (in-place)
  k_gemm<0><<<gb, 256, 0, stream>>>(Yf, W2, nullptr, nullptr, nullptr, nullptr, nullptr,
                                    nullptr, nullptr, nullptr, Xf, NH, N);
  k_gather<true><<<agb, 256, 0, stream>>>(Xf, dinv, offs, ssrc, b2,
                                          Yf, gam, bet, Yf, N);

  // GRU: R -> d_out[0,NH), Z -> d_out[NH,2NH), then fused n+output overwrites both
  k_gemm<1><<<gb, 256, 0, stream>>>(Yf, Wih, hp, Whh, nullptr, bih, bhh,
                                    nullptr, nullptr, nullptr, Rbuf, NH, N);
  k_gemm<1><<<gb, 256, 0, stream>>>(Yf, Wih + 16384, hp, Whh + 16384, nullptr,
                                    bih + 128, bhh + 128,
                                    nullptr, nullptr, nullptr, Zbuf, NH, N);
  k_gemm<2><<<gb, 256, 0, stream>>>(hp, Whh + 32768, Yf, Wih + 32768,
                                    bhh + 256, bih + 256, nullptr,
                                    Rbuf, Zbuf, hp, ofp, NH, N);
}